// Round 13
// baseline (206.627 us; speedup 1.0000x reference)
//
#include <hip/hip_runtime.h>
#include <math.h>

#define BB 1024
#define NN 512
#define MM 256
#define OUTROW (NN + MM + NN * MM)   // 131840
#define EPS_ADD 1e-16f
#define EPS_COS 1e-8f
#define G_REG 11                     // register-resident groups per wave (44 rows)
#define G_LDS 4                      // LDS-resident groups per wave (16 rows, burst-loaded)
#define G_TOT 16                     // total 4-row groups per wave (64 rows)

typedef float f4v __attribute__((ext_vector_type(4)));

__device__ inline float waveReduceSum(float v) {
#pragma unroll
    for (int off = 32; off > 0; off >>= 1) v += __shfl_xor(v, off);
    return v;
}

__device__ __forceinline__ void ldgrp(f4v (&buf)[4], const float* __restrict__ rp) {
#pragma unroll
    for (int mc = 0; mc < 4; ++mc)
        buf[mc] = *reinterpret_cast<const f4v*>(rp + mc * 64);
}
__device__ __forceinline__ void ldgrp_nt(f4v (&buf)[4], const float* __restrict__ rp) {
#pragma unroll
    for (int mc = 0; mc < 4; ++mc)
        buf[mc] = __builtin_nontemporal_load(reinterpret_cast<const f4v*>(rp + mc * 64));
}

__device__ __forceinline__ void redgrp(const f4v (&buf)[4], const f4v (&kf)[4],
                                       float bet, float kn, float* __restrict__ sc,
                                       int row, int sl) {
    float dot = 0.f, ssq = 0.f;
#pragma unroll
    for (int mc = 0; mc < 4; ++mc) {
        const float mx = buf[mc].x + EPS_ADD, my = buf[mc].y + EPS_ADD;
        const float mz = buf[mc].z + EPS_ADD, mw = buf[mc].w + EPS_ADD;
        dot += mx * kf[mc].x + my * kf[mc].y + mz * kf[mc].z + mw * kf[mc].w;
        ssq += mx * mx + my * my + mz * mz + mw * mw;
    }
#pragma unroll
    for (int off = 8; off > 0; off >>= 1) {
        dot += __shfl_xor(dot, off);
        ssq += __shfl_xor(ssq, off);
    }
    if (sl == 0)
        sc[row] = bet * dot / (fmaxf(sqrtf(ssq), EPS_COS) * kn);
}

__device__ __forceinline__ void procgrp(const f4v (&mvv)[4], float wn,
                                        const f4v (&ev)[4], const f4v (&av)[4],
                                        f4v (&acc)[4], float* __restrict__ op) {
#pragma unroll
    for (int mc = 0; mc < 4; ++mc) {
        const f4v nm = mvv[mc] * (1.f - wn * ev[mc]) + wn * av[mc];
        __builtin_nontemporal_store(nm, reinterpret_cast<f4v*>(op + mc * 64));
        acc[mc] += wn * mvv[mc];
    }
}

__global__ __launch_bounds__(512, 2) void ntm_memory_kernel(
    const float* __restrict__ memory, const float* __restrict__ key,
    const float* __restrict__ beta, const float* __restrict__ g,
    const float* __restrict__ s, const float* __restrict__ gamma,
    const float* __restrict__ w_prev, const float* __restrict__ e,
    const float* __restrict__ a, float* __restrict__ out) {
    const int b    = blockIdx.x;
    const int t    = threadIdx.x;
    const int lane = t & 63;
    const int wave = t >> 6;          // 0..7
    const int sub  = lane >> 4;       // 0..3  row within group
    const int sl   = lane & 15;       // 0..15 lanes per row

    __shared__ float key_lds[MM];
    __shared__ float sc[NN];
    __shared__ float wg[NN];
    __shared__ float wf[NN];
    __shared__ float ea_lds[2 * MM];
    __shared__ float red[8];
    __shared__ float rpart[8][MM];
    __shared__ float TL[8 * G_LDS * 4 * MM];   // 128 KB: 16 rows/wave, linear rows

    const float* __restrict__ memb = memory + (size_t)b * NN * MM;
    float* __restrict__ outb       = out + (size_t)b * OUTROW;

    // ---- stage key (+eps), e, a ----
    if (t < MM) {
        key_lds[t]      = key[b * MM + t] + EPS_ADD;
        ea_lds[MM + t]  = a[b * MM + t];
    } else {
        const int i = t - MM;
        ea_lds[i] = e[b * MM + i];
    }
    __syncthreads();

    // ---- key norm ----
    if (t < MM) {
        float kv = key_lds[t];
        float ss = waveReduceSum(kv * kv);
        if (lane == 0) red[wave] = ss;
    }
    __syncthreads();
    const float kn  = fmaxf(sqrtf(red[0] + red[1] + red[2] + red[3]), EPS_COS);
    const float bet = beta[b];
    const float gv  = g[b];
    const float gam = gamma[b];
    const float s0  = s[b * 3 + 0];
    const float s1  = s[b * 3 + 1];
    const float s2  = s[b * 3 + 2];
    __syncthreads();   // red about to be reused

    const int rowbase = wave * 64 + sub;          // row of group gp = rowbase + 4*gp
    const float* __restrict__ rp0 = memb + (size_t)rowbase * MM + sl * 4;

    f4v kf[4];
#pragma unroll
    for (int mc = 0; mc < 4; ++mc)
        kf[mc] = *reinterpret_cast<const f4v*>(&key_lds[mc * 64 + sl * 4]);

    // ---- phase 1a: register tile burst (44 live-out NT loads) ----
    f4v tile[G_REG][4];
#pragma unroll
    for (int gp = 0; gp < G_REG; ++gp)
        ldgrp_nt(tile[gp], rp0 + (size_t)(4 * gp) * MM);

    // ---- phase 1b issue: 16 rows/wave straight to LDS, zero VALU deps.
    // lane i's 16 B -> TLrow + i*16 (linear), src = row + lane*4 floats (HBM).
    {
#pragma unroll
        for (int gl = 0; gl < G_LDS; ++gl) {
#pragma unroll
            for (int rr = 0; rr < 4; ++rr) {
                const int ldsrow = (wave * G_LDS + gl) * 4 + rr;
                const float* src = memb + (size_t)(wave * 64 + 4 * (G_REG + gl) + rr) * MM + lane * 4;
                __builtin_amdgcn_global_load_lds(
                    (const __attribute__((address_space(1))) void*)src,
                    (__attribute__((address_space(3))) void*)&TL[ldsrow * MM],
                    16, 0, 0);
            }
        }
    }

    // ---- phase 1c issue: group 15, cacheable (phase 2 re-reads it via L2) ----
    f4v sS[4];
    ldgrp(sS, rp0 + (size_t)(4 * (G_REG + G_LDS)) * MM);

    // ---- reduce register groups (vmcnt staggers through the burst) ----
#pragma unroll
    for (int gp = 0; gp < G_REG; ++gp)
        redgrp(tile[gp], kf, bet, kn, sc, rowbase + 4 * gp, sl);

    // wait for the TL burst (per-wave vmcnt covers our own global_load_lds)
    asm volatile("s_waitcnt vmcnt(0)" ::: "memory");

    // ---- reduce LDS groups (loads already landed; pure LDS+VALU) ----
#pragma unroll
    for (int gl = 0; gl < G_LDS; ++gl) {
        const float* TLrow = &TL[((wave * G_LDS + gl) * 4 + sub) * MM];
        f4v bufL[4];
#pragma unroll
        for (int mc = 0; mc < 4; ++mc)
            bufL[mc] = *reinterpret_cast<const f4v*>(TLrow + mc * 64 + sl * 4);
        redgrp(bufL, kf, bet, kn, sc, rowbase + 4 * (G_REG + gl), sl);
    }
    // group 15
    redgrp(sS, kf, bet, kn, sc, rowbase + 4 * (G_REG + G_LDS), sl);
    __syncthreads();

    // ---- softmax over N=512, NO max pass (scores = beta*cos in [-1,1]) ----
    const float v  = sc[t];
    const float ex = __expf(v);
    {
        const float s1w = waveReduceSum(ex);
        if (lane == 0) red[wave] = s1w;
    }
    __syncthreads();
    float esum = 0.f;
#pragma unroll
    for (int k = 0; k < 8; k++) esum += red[k];
    const float w_c = ex / esum;

    // ---- gate + circular conv + sharpen ----
    wg[t] = gv * w_c + (1.f - gv) * w_prev[b * NN + t];
    __syncthreads();
    const float wt = wg[(t + NN - 1) & (NN - 1)] * s0 + wg[t] * s1 +
                     wg[(t + 1) & (NN - 1)] * s2;
    const float wp = __powf(wt, gam);
    {
        const float sw = waveReduceSum(wp);
        if (lane == 0) red[wave] = sw;
    }
    __syncthreads();
    float wsum = 0.f;
#pragma unroll
    for (int k = 0; k < 8; k++) wsum += red[k];
    const float wv = wp / (wsum + EPS_ADD);
    wf[t]   = wv;
    outb[t] = wv;      // output w
    // NO barrier: phase 2 reads wf/TL only within this wave's own slab.

    // ---- phase 2: new_mem + r ----
    f4v ev[4], av[4], acc[4];
#pragma unroll
    for (int mc = 0; mc < 4; ++mc) {
        ev[mc]  = *reinterpret_cast<const f4v*>(&ea_lds[mc * 64 + sl * 4]);
        av[mc]  = *reinterpret_cast<const f4v*>(&ea_lds[MM + mc * 64 + sl * 4]);
        acc[mc] = (f4v)0.f;
    }
    float* __restrict__ ob0 = outb + (NN + MM) + (size_t)rowbase * MM + sl * 4;

    // issue the single streaming re-read early (group 15, L2-resident)
    f4v sS2[4];
    ldgrp(sS2, rp0 + (size_t)(4 * (G_REG + G_LDS)) * MM);

    // register-resident groups: pure compute + NT store
#pragma unroll
    for (int gp = 0; gp < G_REG; ++gp)
        procgrp(tile[gp], wf[rowbase + 4 * gp], ev, av, acc,
                ob0 + (size_t)(4 * gp) * MM);

    // LDS-resident groups (single HBM touch, staged in phase 1)
#pragma unroll
    for (int gl = 0; gl < G_LDS; ++gl) {
        const float* TLrow = &TL[((wave * G_LDS + gl) * 4 + sub) * MM];
        f4v bufL[4];
#pragma unroll
        for (int mc = 0; mc < 4; ++mc)
            bufL[mc] = *reinterpret_cast<const f4v*>(TLrow + mc * 64 + sl * 4);
        procgrp(bufL, wf[rowbase + 4 * (G_REG + gl)], ev, av, acc,
                ob0 + (size_t)(4 * (G_REG + gl)) * MM);
    }
    // tail streaming group
    procgrp(sS2, wf[rowbase + 4 * (G_REG + G_LDS)], ev, av, acc,
            ob0 + (size_t)(4 * (G_REG + G_LDS)) * MM);

    // reduce r partials across the 4 sub-rows of the wave
#pragma unroll
    for (int mc = 0; mc < 4; ++mc) {
        acc[mc].x += __shfl_xor(acc[mc].x, 16); acc[mc].y += __shfl_xor(acc[mc].y, 16);
        acc[mc].z += __shfl_xor(acc[mc].z, 16); acc[mc].w += __shfl_xor(acc[mc].w, 16);
        acc[mc].x += __shfl_xor(acc[mc].x, 32); acc[mc].y += __shfl_xor(acc[mc].y, 32);
        acc[mc].z += __shfl_xor(acc[mc].z, 32); acc[mc].w += __shfl_xor(acc[mc].w, 32);
    }
    if (sub == 0) {
#pragma unroll
        for (int mc = 0; mc < 4; ++mc)
            *reinterpret_cast<f4v*>(&rpart[wave][mc * 64 + sl * 4]) = acc[mc];
    }
    __syncthreads();
    if (t < MM) {
        float rsum = 0.f;
#pragma unroll
        for (int k = 0; k < 8; k++) rsum += rpart[k][t];
        outb[NN + t] = rsum;   // output r
    }
}

extern "C" void kernel_launch(void* const* d_in, const int* in_sizes, int n_in,
                              void* d_out, int out_size, void* d_ws, size_t ws_size,
                              hipStream_t stream) {
    const float* memory = (const float*)d_in[0];
    const float* key    = (const float*)d_in[1];
    const float* beta   = (const float*)d_in[2];
    const float* g      = (const float*)d_in[3];
    const float* s      = (const float*)d_in[4];
    const float* gamma  = (const float*)d_in[5];
    const float* w_prev = (const float*)d_in[6];
    const float* e      = (const float*)d_in[7];
    const float* a      = (const float*)d_in[8];
    float* out = (float*)d_out;

    ntm_memory_kernel<<<BB, 512, 0, stream>>>(memory, key, beta, g, s, gamma,
                                              w_prev, e, a, out);
}

// Round 14
// 205.715 us; speedup vs baseline: 1.0044x; 1.0044x over previous
//
#include <hip/hip_runtime.h>
#include <math.h>

#define BB 1024
#define NN 512
#define MM 256
#define OUTROW (NN + MM + NN * MM)   // 131840
#define EPS_ADD 1e-16f
#define EPS_COS 1e-8f
#define G_REG 11                     // register-resident groups per wave (44 rows)
#define G_LDS 4                      // LDS groups per wave (16 rows, fly during bubble)
#define G_TOT 16                     // total 4-row groups per wave (64 rows)

typedef float f4v __attribute__((ext_vector_type(4)));

__device__ inline float waveReduceSum(float v) {
#pragma unroll
    for (int off = 32; off > 0; off >>= 1) v += __shfl_xor(v, off);
    return v;
}

__device__ __forceinline__ void ldgrp(f4v (&buf)[4], const float* __restrict__ rp) {
#pragma unroll
    for (int mc = 0; mc < 4; ++mc)
        buf[mc] = *reinterpret_cast<const f4v*>(rp + mc * 64);
}
__device__ __forceinline__ void ldgrp_nt(f4v (&buf)[4], const float* __restrict__ rp) {
#pragma unroll
    for (int mc = 0; mc < 4; ++mc)
        buf[mc] = __builtin_nontemporal_load(reinterpret_cast<const f4v*>(rp + mc * 64));
}

__device__ __forceinline__ void redgrp(const f4v (&buf)[4], const f4v (&kf)[4],
                                       float bet, float kn, float* __restrict__ sc,
                                       int row, int sl) {
    float dot = 0.f, ssq = 0.f;
#pragma unroll
    for (int mc = 0; mc < 4; ++mc) {
        const float mx = buf[mc].x + EPS_ADD, my = buf[mc].y + EPS_ADD;
        const float mz = buf[mc].z + EPS_ADD, mw = buf[mc].w + EPS_ADD;
        dot += mx * kf[mc].x + my * kf[mc].y + mz * kf[mc].z + mw * kf[mc].w;
        ssq += mx * mx + my * my + mz * mz + mw * mw;
    }
#pragma unroll
    for (int off = 8; off > 0; off >>= 1) {
        dot += __shfl_xor(dot, off);
        ssq += __shfl_xor(ssq, off);
    }
    if (sl == 0)
        sc[row] = bet * dot / (fmaxf(sqrtf(ssq), EPS_COS) * kn);
}

__device__ __forceinline__ void procgrp(const f4v (&mvv)[4], float wn,
                                        const f4v (&ev)[4], const f4v (&av)[4],
                                        f4v (&acc)[4], float* __restrict__ op) {
#pragma unroll
    for (int mc = 0; mc < 4; ++mc) {
        const f4v nm = mvv[mc] * (1.f - wn * ev[mc]) + wn * av[mc];
        __builtin_nontemporal_store(nm, reinterpret_cast<f4v*>(op + mc * 64));
        acc[mc] += wn * mvv[mc];
    }
}

// cross-wave LDS handshake WITHOUT draining vmcnt (keeps global_load_lds in flight)
__device__ __forceinline__ void lds_barrier() {
    asm volatile("s_waitcnt lgkmcnt(0)" ::: "memory");
    __builtin_amdgcn_s_barrier();
}

__global__ __launch_bounds__(512, 2) void ntm_memory_kernel(
    const float* __restrict__ memory, const float* __restrict__ key,
    const float* __restrict__ beta, const float* __restrict__ g,
    const float* __restrict__ s, const float* __restrict__ gamma,
    const float* __restrict__ w_prev, const float* __restrict__ e,
    const float* __restrict__ a, float* __restrict__ out) {
    const int b    = blockIdx.x;
    const int t    = threadIdx.x;
    const int lane = t & 63;
    const int wave = t >> 6;          // 0..7
    const int sub  = lane >> 4;       // 0..3  row within group
    const int sl   = lane & 15;       // 0..15 lanes per row

    __shared__ float key_lds[MM];
    __shared__ float sc[NN];
    __shared__ float wg[NN];
    __shared__ float wf[NN];
    __shared__ float ea_lds[2 * MM];
    __shared__ float red[8];
    __shared__ float rpart[8][MM];
    __shared__ float TL[8 * G_LDS * 4 * MM];   // 128 KB: 16 rows/wave, linear rows

    const float* __restrict__ memb = memory + (size_t)b * NN * MM;
    float* __restrict__ outb       = out + (size_t)b * OUTROW;

    // ---- stage key (+eps), e, a ----
    if (t < MM) {
        key_lds[t]      = key[b * MM + t] + EPS_ADD;
        ea_lds[MM + t]  = a[b * MM + t];
    } else {
        const int i = t - MM;
        ea_lds[i] = e[b * MM + i];
    }
    __syncthreads();

    // ---- key norm ----
    if (t < MM) {
        float kv = key_lds[t];
        float ss = waveReduceSum(kv * kv);
        if (lane == 0) red[wave] = ss;
    }
    __syncthreads();
    const float kn  = fmaxf(sqrtf(red[0] + red[1] + red[2] + red[3]), EPS_COS);
    const float bet = beta[b];
    const float gv  = g[b];
    const float gam = gamma[b];
    const float s0  = s[b * 3 + 0];
    const float s1  = s[b * 3 + 1];
    const float s2  = s[b * 3 + 2];
    __syncthreads();   // red about to be reused

    const int rowbase = wave * 64 + sub;          // row of group gp = rowbase + 4*gp
    const float* __restrict__ rp0 = memb + (size_t)rowbase * MM + sl * 4;

    f4v kf[4];
#pragma unroll
    for (int mc = 0; mc < 4; ++mc)
        kf[mc] = *reinterpret_cast<const f4v*>(&key_lds[mc * 64 + sl * 4]);

    // ---- phase 1a: register tile (44 live-out NT loads => deep MLP) ----
    f4v tile[G_REG][4];
#pragma unroll
    for (int gp = 0; gp < G_REG; ++gp)
        ldgrp_nt(tile[gp], rp0 + (size_t)(4 * gp) * MM);

    // reduce register groups (vmcnt staggers through the burst)
#pragma unroll
    for (int gp = 0; gp < G_REG; ++gp)
        redgrp(tile[gp], kf, bet, kn, sc, rowbase + 4 * gp, sl);

    // ---- phase 1b: group 15 streamed through registers (cacheable) ----
    f4v sS[4];
    ldgrp(sS, rp0 + (size_t)(4 * (G_REG + G_LDS)) * MM);
    redgrp(sS, kf, bet, kn, sc, rowbase + 4 * (G_REG + G_LDS), sl);

    // ---- issue groups 11..14 HBM->LDS NOW; they fly through the softmax
    // bubble (raw barriers below do NOT drain vmcnt).
    {
#pragma unroll
        for (int gl = 0; gl < G_LDS; ++gl) {
#pragma unroll
            for (int rr = 0; rr < 4; ++rr) {
                const int ldsrow = (wave * G_LDS + gl) * 4 + rr;
                const float* src = memb + (size_t)(wave * 64 + 4 * (G_REG + gl) + rr) * MM + lane * 4;
                __builtin_amdgcn_global_load_lds(
                    (const __attribute__((address_space(1))) void*)src,
                    (__attribute__((address_space(3))) void*)&TL[ldsrow * MM],
                    16, 0, 0);
            }
        }
    }

    // groups 11..14 still need their scores: re-read via L2 (phase-1 rows are
    // cache-hot) through registers, 2-deep — this also covers TL flight time.
    {
        f4v sA[4], sB[4];
        ldgrp(sA, rp0 + (size_t)(4 * (G_REG + 0)) * MM);
        ldgrp(sB, rp0 + (size_t)(4 * (G_REG + 1)) * MM);
        redgrp(sA, kf, bet, kn, sc, rowbase + 4 * (G_REG + 0), sl);
        ldgrp(sA, rp0 + (size_t)(4 * (G_REG + 2)) * MM);
        redgrp(sB, kf, bet, kn, sc, rowbase + 4 * (G_REG + 1), sl);
        ldgrp(sB, rp0 + (size_t)(4 * (G_REG + 3)) * MM);
        redgrp(sA, kf, bet, kn, sc, rowbase + 4 * (G_REG + 2), sl);
        redgrp(sB, kf, bet, kn, sc, rowbase + 4 * (G_REG + 3), sl);
    }
    // NO barrier here: sc[t] is wave-local (thread t's row written by its own
    // wave; same-wave DS ops are ordered). TL loads stay in flight.

    // ---- softmax over N=512, NO max pass (scores = beta*cos in [-1,1]) ----
    const float v  = sc[t];
    const float ex = __expf(v);
    {
        const float s1w = waveReduceSum(ex);
        if (lane == 0) red[wave] = s1w;
    }
    lds_barrier();                    // cross-wave red[] exchange, vmcnt untouched
    float esum = 0.f;
#pragma unroll
    for (int k = 0; k < 8; k++) esum += red[k];
    const float w_c = ex / esum;

    // ---- gate + circular conv + sharpen ----
    wg[t] = gv * w_c + (1.f - gv) * w_prev[b * NN + t];
    lds_barrier();                    // wg[t±1] crosses wave slabs
    const float wt = wg[(t + NN - 1) & (NN - 1)] * s0 + wg[t] * s1 +
                     wg[(t + 1) & (NN - 1)] * s2;
    const float wp = __powf(wt, gam);
    {
        const float sw = waveReduceSum(wp);
        if (lane == 0) red[wave] = sw;
    }
    lds_barrier();                    // cross-wave red[] exchange
    float wsum = 0.f;
#pragma unroll
    for (int k = 0; k < 8; k++) wsum += red[k];
    const float wv = wp / (wsum + EPS_ADD);
    wf[t]   = wv;
    outb[t] = wv;      // output w
    // NO barrier: phase 2 reads wf/TL only within this wave's own slab.

    // now (and only now) require the bubble-time TL loads to have landed
    asm volatile("s_waitcnt vmcnt(0)" ::: "memory");
    __builtin_amdgcn_sched_barrier(0);

    // ---- phase 2: new_mem + r ----
    f4v ev[4], av[4], acc[4];
#pragma unroll
    for (int mc = 0; mc < 4; ++mc) {
        ev[mc]  = *reinterpret_cast<const f4v*>(&ea_lds[mc * 64 + sl * 4]);
        av[mc]  = *reinterpret_cast<const f4v*>(&ea_lds[MM + mc * 64 + sl * 4]);
        acc[mc] = (f4v)0.f;
    }
    float* __restrict__ ob0 = outb + (NN + MM) + (size_t)rowbase * MM + sl * 4;

    // issue the single streaming re-read early (group 15, L2-resident)
    f4v sS2[4];
    ldgrp(sS2, rp0 + (size_t)(4 * (G_REG + G_LDS)) * MM);

    // register-resident groups: pure compute + NT store
#pragma unroll
    for (int gp = 0; gp < G_REG; ++gp)
        procgrp(tile[gp], wf[rowbase + 4 * gp], ev, av, acc,
                ob0 + (size_t)(4 * gp) * MM);

    // LDS-resident groups (arrived during the bubble)
#pragma unroll
    for (int gl = 0; gl < G_LDS; ++gl) {
        const float* TLrow = &TL[((wave * G_LDS + gl) * 4 + sub) * MM];
        f4v bufL[4];
#pragma unroll
        for (int mc = 0; mc < 4; ++mc)
            bufL[mc] = *reinterpret_cast<const f4v*>(TLrow + mc * 64 + sl * 4);
        procgrp(bufL, wf[rowbase + 4 * (G_REG + gl)], ev, av, acc,
                ob0 + (size_t)(4 * (G_REG + gl)) * MM);
    }
    // tail streaming group
    procgrp(sS2, wf[rowbase + 4 * (G_REG + G_LDS)], ev, av, acc,
            ob0 + (size_t)(4 * (G_REG + G_LDS)) * MM);

    // reduce r partials across the 4 sub-rows of the wave
#pragma unroll
    for (int mc = 0; mc < 4; ++mc) {
        acc[mc].x += __shfl_xor(acc[mc].x, 16); acc[mc].y += __shfl_xor(acc[mc].y, 16);
        acc[mc].z += __shfl_xor(acc[mc].z, 16); acc[mc].w += __shfl_xor(acc[mc].w, 16);
        acc[mc].x += __shfl_xor(acc[mc].x, 32); acc[mc].y += __shfl_xor(acc[mc].y, 32);
        acc[mc].z += __shfl_xor(acc[mc].z, 32); acc[mc].w += __shfl_xor(acc[mc].w, 32);
    }
    if (sub == 0) {
#pragma unroll
        for (int mc = 0; mc < 4; ++mc)
            *reinterpret_cast<f4v*>(&rpart[wave][mc * 64 + sl * 4]) = acc[mc];
    }
    __syncthreads();
    if (t < MM) {
        float rsum = 0.f;
#pragma unroll
        for (int k = 0; k < 8; k++) rsum += rpart[k][t];
        outb[NN + t] = rsum;   // output r
    }
}

extern "C" void kernel_launch(void* const* d_in, const int* in_sizes, int n_in,
                              void* d_out, int out_size, void* d_ws, size_t ws_size,
                              hipStream_t stream) {
    const float* memory = (const float*)d_in[0];
    const float* key    = (const float*)d_in[1];
    const float* beta   = (const float*)d_in[2];
    const float* g      = (const float*)d_in[3];
    const float* s      = (const float*)d_in[4];
    const float* gamma  = (const float*)d_in[5];
    const float* w_prev = (const float*)d_in[6];
    const float* e      = (const float*)d_in[7];
    const float* a      = (const float*)d_in[8];
    float* out = (float*)d_out;

    ntm_memory_kernel<<<BB, 512, 0, stream>>>(memory, key, beta, g, s, gamma,
                                              w_prev, e, a, out);
}